// Round 6
// baseline (612.231 us; speedup 1.0000x reference)
//
#include <hip/hip_runtime.h>
#include <stdint.h>

#define M_DIM 4096   // BATCH*SEQ
#define N_DIM 16384  // OUT_FEATURES
#define K_DIM 4096   // IN_FEATURES
#define BM 256
#define BN 256
#define BK 64
#define NT (K_DIM / BK)   // 64 K-tiles

typedef __attribute__((ext_vector_type(8))) __bf16 bf16x8;
typedef __attribute__((ext_vector_type(4))) float f32x4;

// fp32 -> bf16 bits, round-to-nearest-even
__device__ __forceinline__ unsigned short f2bf(float f) {
    uint32_t u = __builtin_bit_cast(uint32_t, f);
    uint32_t r = (u + 0x7FFFu + ((u >> 16) & 1u)) >> 16;
    return (unsigned short)r;
}

union Pack8 { unsigned short h[8]; uint4 v; };

__device__ __forceinline__ void async_copy16(const void* g, void* l) {
    __builtin_amdgcn_global_load_lds((__attribute__((address_space(1))) void*)(g),
                                     (__attribute__((address_space(3))) void*)(l),
                                     16, 0, 0);
}

#define BARRIER() do { asm volatile("" ::: "memory"); \
                       __builtin_amdgcn_s_barrier();  \
                       asm volatile("" ::: "memory"); } while (0)

// ---------------- phase 0: cast x fp32 -> bf16 ----------------
__global__ __launch_bounds__(256) void cast_x_kernel(const float* __restrict__ x,
                                                     unsigned short* __restrict__ xb,
                                                     int n8) {
    for (int i = blockIdx.x * blockDim.x + threadIdx.x; i < n8;
         i += gridDim.x * blockDim.x) {
        const float4* p = (const float4*)(x + (size_t)i * 8);
        float4 v0 = p[0], v1 = p[1];
        Pack8 o;
        o.h[0] = f2bf(v0.x); o.h[1] = f2bf(v0.y);
        o.h[2] = f2bf(v0.z); o.h[3] = f2bf(v0.w);
        o.h[4] = f2bf(v1.x); o.h[5] = f2bf(v1.y);
        o.h[6] = f2bf(v1.z); o.h[7] = f2bf(v1.w);
        *(uint4*)(xb + (size_t)i * 8) = o.v;
    }
}

// ---------------- phase 1: dequant weights -> bf16 ----------------
__global__ __launch_bounds__(256) void dequant_kernel(const int* __restrict__ stored,
                                                      const int* __restrict__ sign,
                                                      const float* __restrict__ log_min,
                                                      const float* __restrict__ log_max,
                                                      unsigned short* __restrict__ wb,
                                                      int n8) {
    const float lmin = log_min[0];
    const float lrange = log_max[0] - lmin;
    for (int i = blockIdx.x * blockDim.x + threadIdx.x; i < n8;
         i += gridDim.x * blockDim.x) {
        const int4* ps = (const int4*)(stored + (size_t)i * 8);
        const int4* pg = (const int4*)(sign + (size_t)i * 8);
        int4 s0 = ps[0], s1 = ps[1];
        int4 g0 = pg[0], g1 = pg[1];
        int sv[8] = {s0.x, s0.y, s0.z, s0.w, s1.x, s1.y, s1.z, s1.w};
        int gv[8] = {g0.x, g0.y, g0.z, g0.w, g1.x, g1.y, g1.z, g1.w};
        Pack8 o;
#pragma unroll
        for (int j = 0; j < 8; ++j) {
            float nrm = (255.0f - (float)sv[j]) * (1.0f / 254.0f);
            float w = __expf(lmin + nrm * lrange);
            o.h[j] = f2bf(gv[j] ? w : -w);
        }
        *(uint4*)(wb + (size_t)i * 8) = o.v;
    }
}

// ---------------- phase 2: 256x256 bf16 GEMM, 1-barrier/K-tile, A triple-buffered ----------------
// A: [M][K] bf16, W: [N][K] bf16, C: [M][N] fp32
// LDS 160 KiB: A buf p (p=t%3) at p*32768 (halves at +h*16384; 128 rows x 128 B,
// swizzled); B buf c (c=t&1) at 98304 + c*32768 (halves at +h*16384).
// Swizzle involution: byte ^= ((row&7)<<4); global_load_lds dest linear, global
// SOURCE pre-inverse-swizzled, same XOR on ds_read (rule #21).
//
// Per K-tile t:
//   top:  vmcnt(4) [A(t),B(t) landed; A(t+1) in flight]; BARRIER;
//         issue B(t+1) -> B buf c^1 (4 loads) + A(t+2) -> A buf (t+2)%3 (4 loads)
//   q0:   read aF0(8) + bF0(4) + bF1(4);  MFMA aF0 x bF0
//   q1:   read aF1(8);                    MFMA aF0 x bF1
//   q2:                                   MFMA aF1 x bF0
//   q3:                                   MFMA aF1 x bF1
// Hazards: B(t+1) overwrites B(t-1) (read only in tile t-1, done at top barrier);
// A(t+2) overwrites A(t-1) (same). One barrier/tile; skew bounded < 1 tile.
// vmcnt ledger at top of t: [A(t) 4, B(t) 4, A(t+1) 4] -> wait 4 leaves A(t+1).
__global__ __launch_bounds__(512, 2) void gemm_kernel(const unsigned short* __restrict__ A,
                                                      const unsigned short* __restrict__ W,
                                                      const float* __restrict__ bias,
                                                      float* __restrict__ C) {
    extern __shared__ char lds[];
    const int tid  = threadIdx.x;
    const int wave = tid >> 6;
    const int lane = tid & 63;
    const int l15  = lane & 15;
    const int l16  = lane >> 4;
    const int wr   = wave >> 2;   // 0..1 -> 128-row band (A half wr)
    const int wc   = wave & 3;    // 0..3 -> 64-col band (B half wc>>1, rows (wc&1)*64)

    // T1: XCD swizzle. nwg=1024 (%8==0); each XCD: 2 M-rows x all N -> A panel L2-hot.
    const int bid = blockIdx.x;
    const int wg  = ((bid & 7) << 7) | (bid >> 3);
    const int rowBase = (wg >> 6) * BM;
    const int colBase = (wg & 63) * BN;

    f32x4 acc[8][4] = {};

    // stage one half-tile u (0=A.h0,1=A.h1,2=B.h0,3=B.h1) of tile t
    auto stage_half = [&](int t, int u) {
        const int kb = t * BK;
        const unsigned short* g = (u < 2) ? A : W;
        const int rb = ((u < 2) ? rowBase : colBase) + (u & 1) * 128;
        char* hb = lds + ((u < 2) ? (t % 3) * 32768
                                  : 98304 + (t & 1) * 32768) + (u & 1) * 16384;
#pragma unroll
        for (int sub = 0; sub < 2; ++sub) {
            const int Ld   = (sub * 512 + tid) * 16;              // linear dest byte
            const int r    = Ld >> 7;                             // row (128 B/row)
            const int colb = (Ld & 127) ^ ((r & 7) << 4);         // inverse-swz source
            async_copy16(g + (size_t)(rb + r) * K_DIM + kb + (colb >> 1),
                         hb + (sub * 512 + wave * 64) * 16);      // wave-uniform dest
        }
    };

    // prologue: A(0), B(0), A(1)  (12 loads outstanding)
    stage_half(0, 0); stage_half(0, 1);
    stage_half(0, 2); stage_half(0, 3);
    stage_half(1, 0); stage_half(1, 1);

    for (int t = 0; t < NT; ++t) {
        if (t + 1 < NT) asm volatile("s_waitcnt vmcnt(4)" ::: "memory");
        else            asm volatile("s_waitcnt vmcnt(0)" ::: "memory");
        BARRIER();
        __builtin_amdgcn_sched_barrier(0);

        // all staging for the pipeline issues at tile top (latency hidden under 4 quadrants)
        if (t + 1 < NT) { stage_half(t + 1, 2); stage_half(t + 1, 3); }
        if (t + 2 < NT) { stage_half(t + 2, 0); stage_half(t + 2, 1); }

        const char* bA  = lds + (t % 3) * 32768 + wr * 16384;
        const char* bB  = lds + 98304 + (t & 1) * 32768 + (wc >> 1) * 16384;
        const int   brB = (wc & 1) * 64;

        bf16x8 aF0[4][2], aF1[4][2], bF0[2][2], bF1[2][2];

        // ---- q0: reads, then MFMA quadrant (0,0) ----
#pragma unroll
        for (int i = 0; i < 4; ++i)
#pragma unroll
            for (int ks = 0; ks < 2; ++ks) {
                const int r    = i * 16 + l15;                     // rows 0..63
                const int colb = (ks * 64 + l16 * 16) ^ ((r & 7) << 4);
                aF0[i][ks] = *(const bf16x8*)(bA + (r << 7) + colb);
            }
#pragma unroll
        for (int j = 0; j < 2; ++j)
#pragma unroll
            for (int ks = 0; ks < 2; ++ks) {
                const int r    = brB + j * 16 + l15;
                const int colb = (ks * 64 + l16 * 16) ^ ((r & 7) << 4);
                bF0[j][ks] = *(const bf16x8*)(bB + (r << 7) + colb);
            }
#pragma unroll
        for (int j = 0; j < 2; ++j)
#pragma unroll
            for (int ks = 0; ks < 2; ++ks) {
                const int r    = brB + 32 + j * 16 + l15;
                const int colb = (ks * 64 + l16 * 16) ^ ((r & 7) << 4);
                bF1[j][ks] = *(const bf16x8*)(bB + (r << 7) + colb);
            }
        __builtin_amdgcn_s_setprio(1);
#pragma unroll
        for (int i = 0; i < 4; ++i)
#pragma unroll
            for (int j = 0; j < 2; ++j)
#pragma unroll
                for (int ks = 0; ks < 2; ++ks)
                    acc[i][j] = __builtin_amdgcn_mfma_f32_16x16x32_bf16(
                        aF0[i][ks], bF0[j][ks], acc[i][j], 0, 0, 0);
        __builtin_amdgcn_s_setprio(0);

        // ---- q1: A-prefetch rows 64..127, MFMA quadrant (0,1) ----
#pragma unroll
        for (int i = 0; i < 4; ++i)
#pragma unroll
            for (int ks = 0; ks < 2; ++ks) {
                const int r    = 64 + i * 16 + l15;
                const int colb = (ks * 64 + l16 * 16) ^ ((r & 7) << 4);
                aF1[i][ks] = *(const bf16x8*)(bA + (r << 7) + colb);
            }
        __builtin_amdgcn_s_setprio(1);
#pragma unroll
        for (int i = 0; i < 4; ++i)
#pragma unroll
            for (int j = 0; j < 2; ++j)
#pragma unroll
                for (int ks = 0; ks < 2; ++ks)
                    acc[i][2 + j] = __builtin_amdgcn_mfma_f32_16x16x32_bf16(
                        aF0[i][ks], bF1[j][ks], acc[i][2 + j], 0, 0, 0);
        __builtin_amdgcn_s_setprio(0);

        // ---- q2: MFMA quadrant (1,0) ----
        __builtin_amdgcn_s_setprio(1);
#pragma unroll
        for (int i = 0; i < 4; ++i)
#pragma unroll
            for (int j = 0; j < 2; ++j)
#pragma unroll
                for (int ks = 0; ks < 2; ++ks)
                    acc[4 + i][j] = __builtin_amdgcn_mfma_f32_16x16x32_bf16(
                        aF1[i][ks], bF0[j][ks], acc[4 + i][j], 0, 0, 0);
        __builtin_amdgcn_s_setprio(0);

        // ---- q3: MFMA quadrant (1,1) ----
        __builtin_amdgcn_s_setprio(1);
#pragma unroll
        for (int i = 0; i < 4; ++i)
#pragma unroll
            for (int j = 0; j < 2; ++j)
#pragma unroll
                for (int ks = 0; ks < 2; ++ks)
                    acc[4 + i][2 + j] = __builtin_amdgcn_mfma_f32_16x16x32_bf16(
                        aF1[i][ks], bF1[j][ks], acc[4 + i][2 + j], 0, 0, 0);
        __builtin_amdgcn_s_setprio(0);
    }

    // epilogue: C/D layout col=lane&15, row=(lane>>4)*4+reg (m89/m91-verified)
#pragma unroll
    for (int m = 0; m < 8; ++m) {
        const int grow0 = rowBase + wr * 128 + m * 16 + l16 * 4;
#pragma unroll
        for (int n = 0; n < 4; ++n) {
            const int gcol = colBase + wc * 64 + n * 16 + l15;
            const float bv = bias[gcol];
#pragma unroll
            for (int r4 = 0; r4 < 4; ++r4)
                C[(size_t)(grow0 + r4) * N_DIM + gcol] = acc[m][n][r4] + bv;
        }
    }
}

extern "C" void kernel_launch(void* const* d_in, const int* in_sizes, int n_in,
                              void* d_out, int out_size, void* d_ws, size_t ws_size,
                              hipStream_t stream) {
    const float* x       = (const float*)d_in[0];
    const int*   stored  = (const int*)d_in[1];
    const int*   sign    = (const int*)d_in[2];
    const float* log_min = (const float*)d_in[3];
    const float* log_max = (const float*)d_in[4];
    const float* bias    = (const float*)d_in[5];
    float* out = (float*)d_out;

    unsigned short* Ab = (unsigned short*)d_ws;                         // 32 MB
    unsigned short* Wb = (unsigned short*)((char*)d_ws +
                          (size_t)M_DIM * K_DIM * sizeof(unsigned short)); // +128 MB

    cast_x_kernel<<<2048, 256, 0, stream>>>(x, Ab, (M_DIM * K_DIM) / 8);
    dequant_kernel<<<4096, 256, 0, stream>>>(stored, sign, log_min, log_max, Wb,
                                             (N_DIM * K_DIM) / 8);

    hipFuncSetAttribute((const void*)gemm_kernel,
                        hipFuncAttributeMaxDynamicSharedMemorySize, 163840);
    gemm_kernel<<<dim3((M_DIM / BM) * (N_DIM / BN)), dim3(512), 163840, stream>>>(
        Ab, Wb, bias, out);
}